// Round 8
// baseline (325.073 us; speedup 1.0000x reference)
//
#include <hip/hip_runtime.h>
#include <hip/hip_bf16.h>
#include <math.h>
#include <stdint.h>

typedef __attribute__((ext_vector_type(8))) short short8;
typedef __attribute__((ext_vector_type(4))) float f32x4;

__device__ inline short f2bf(float x) {
  union { float f; uint32_t u; } c; c.f = x;
  uint32_t r = (c.u + 0x7FFFu + ((c.u >> 16) & 1u)) >> 16;
  return (short)(uint16_t)r;
}
__device__ inline float bf2f(short s) {
  union { uint32_t u; float f; } c; c.u = ((uint32_t)(uint16_t)s) << 16;
  return c.f;
}

__device__ inline void gload16(const short* src, const char* ldsdst) {
  __builtin_amdgcn_global_load_lds(
      (const __attribute__((address_space(1))) void*)src,
      (__attribute__((address_space(3))) void*)ldsdst, 16, 0, 0);
}

#define BAR __builtin_amdgcn_s_barrier()
// tile-end wait: certify previous tile's A-staging across waves (vmcnt counted,
// never 0 in steady state) + ensure this tile's ds_reads were serviced.
#define WAIT6 asm volatile("s_waitcnt vmcnt(6) lgkmcnt(0)" ::: "memory")
#define WAIT4 asm volatile("s_waitcnt vmcnt(4) lgkmcnt(0)" ::: "memory")
#define WAIT2 asm volatile("s_waitcnt vmcnt(2) lgkmcnt(0)" ::: "memory")

// ---------------- prep: f32 -> bf16 for X and Kp in one launch ----------------
__global__ void cvt2_kernel(const float* __restrict__ X, const float* __restrict__ Kp,
                            short* __restrict__ Xb, short* __restrict__ Kb,
                            int n8x, int n8tot) {
  int i = blockIdx.x * blockDim.x + threadIdx.x;
  if (i >= n8tot) return;
  const float* src = (i < n8x) ? X + (size_t)i * 8 : Kp + (size_t)(i - n8x) * 8;
  short* dst = (i < n8x) ? Xb + (size_t)i * 8 : Kb + (size_t)(i - n8x) * 8;
  const float4* p = (const float4*)src;
  float4 a = p[0], b = p[1];
  short8 o;
  o[0] = f2bf(a.x); o[1] = f2bf(a.y); o[2] = f2bf(a.z); o[3] = f2bf(a.w);
  o[4] = f2bf(b.x); o[5] = f2bf(b.y); o[6] = f2bf(b.z); o[7] = f2bf(b.w);
  *(short8*)dst = o;
}

// ---------------- prep: V[4096,1024] f32 -> Vt[1024,4096] bf16 ----------------
__global__ void transpose_bf16_kernel(const float* __restrict__ V,
                                      short* __restrict__ Vt,
                                      int rows, int cols) {
  __shared__ float tile[64][65];
  int n0 = blockIdx.x * 64;
  int d0 = blockIdx.y * 64;
  int t = threadIdx.x;
#pragma unroll
  for (int r = 0; r < 16; ++r) {
    int idx = t + 256 * r;
    int rr = idx >> 6, cc = idx & 63;
    tile[rr][cc] = V[(size_t)(n0 + rr) * cols + d0 + cc];
  }
  __syncthreads();
#pragma unroll
  for (int r = 0; r < 16; ++r) {
    int idx = t + 256 * r;
    int dd = idx >> 6, nn = idx & 63;
    Vt[(size_t)(d0 + dd) * rows + n0 + nn] = f2bf(tile[nn][dd]);
  }
}

// ======== hybrid GEMM: C[8192,N] = A[8192,K] x B[N,K]^T ========
// A: staged in LDS (3-buffer ring, BK=32, 48 KiB, swizzled).
// B: direct global->register loads (L1/L2 served), reg double-buffered.
// 8 waves (WM x WN), wave tile (256/WM) x 64. 1 barrier + 1 counted wait/tile.
template <int N, int K, int BN, int WM, int WN, bool SCORE>
__global__ __launch_bounds__(512, 2) void gemm_hyb(
    const short* __restrict__ A, const short* __restrict__ Bm,
    void* __restrict__ Cout, float* __restrict__ rowss) {
  constexpr int NT = K / 32;
  static_assert((NT - 2) % 6 == 0, "unroll-6 tail assumes NT%6==2");
  constexpr int ASZ = 256 * 32 * 2;  // 16 KiB per ring slot
  constexpr int MF = 256 / WM / 16;  // m-frags per wave (8 or 4)
  constexpr int NTN = N / BN;

  __shared__ char lds[3 * ASZ];

  const int t = threadIdx.x, lane = t & 63, w = t >> 6;
  const int wm = w / WN, wn = w % WN;
  const int idx = lane & 15, g = lane >> 4;

  const int bid = blockIdx.x;
  const int id2 = (bid & 7) * (4 * NTN) + (bid >> 3);  // bijective, grid%8==0
  const int row0 = (id2 / NTN) * 256, col0 = (id2 % NTN) * BN;

  // A staging: thread t writes LDS byte t*16; carries logical k-slot
  // (t&3) ^ ((row>>1)&3), row = t>>2  (verified conflict-free in R7)
  const int sxor = ((t & 3) ^ ((t >> 3) & 3)) * 8;
  const short* gAp = A + (size_t)(row0 + (t >> 2)) * K + sxor;

  auto STG = [&](int s, int T) {
    const int kt = T * 32;
    char* base = (char*)lds + s * ASZ + t * 16;
#pragma unroll
    for (int r = 0; r < 2; ++r)
      gload16(gAp + (size_t)(r * 128) * K + kt, base + r * 8192);
  };

  // A read swizzle: logical k-slot g of row r lives at slot g ^ ((r>>1)&3)
  const int rdx = (g ^ ((idx >> 1) & 3)) << 4;
  short8 a[MF], b0[4], b1[4];

  auto LDA = [&](int s) {
    const char* base = (char*)lds + s * ASZ;
#pragma unroll
    for (int f = 0; f < MF; ++f) {
      const int row = wm * (256 / WM) + f * 16 + idx;
      a[f] = *(const short8*)(base + row * 64 + rdx);
    }
  };

  // B fragment: direct global load (16 B/lane, 32 full cache lines/instr)
  const short* gBp = Bm + (size_t)(col0 + wn * 64 + idx) * K + g * 8;
  auto GLB = [&](int T, short8(&bb)[4]) {
    const int kt = T * 32;
#pragma unroll
    for (int nf = 0; nf < 4; ++nf)
      bb[nf] = *(const short8*)(gBp + (size_t)(nf * 16) * K + kt);
  };

  f32x4 acc[MF][4] = {};
  auto MFM = [&](short8(&bb)[4]) {
    __builtin_amdgcn_s_setprio(1);
#pragma unroll
    for (int f = 0; f < MF; ++f)
#pragma unroll
      for (int nf = 0; nf < 4; ++nf)
        acc[f][nf] = __builtin_amdgcn_mfma_f32_16x16x32_bf16(
            a[f], bb[nf], acc[f][nf], 0, 0, 0);
    __builtin_amdgcn_s_setprio(0);
  };

#define BODY(T, S, S2, BC, BN_)  \
  {                              \
    STG(S2, (T) + 2);            \
    GLB((T) + 1, BN_);           \
    LDA(S);                      \
    MFM(BC);                     \
    WAIT6;                       \
    BAR;                         \
  }

  // prologue: stage A tiles 0,1; B tile 0 -> b0; certify A(0) robustly
  STG(0, 0);
  STG(1, 1);
  GLB(0, b0);
  WAIT2;
  BAR;

  for (int c = 0; c < NT - 2; c += 6) {
    BODY(c + 0, 0, 2, b0, b1);
    BODY(c + 1, 1, 0, b1, b0);
    BODY(c + 2, 2, 1, b0, b1);
    BODY(c + 3, 0, 2, b1, b0);
    BODY(c + 4, 1, 0, b0, b1);
    BODY(c + 5, 2, 1, b1, b0);
  }
  // tail: T = NT-2 (s=0, even parity), T = NT-1 (s=1)
  {
    GLB(NT - 1, b1);
    LDA(0);
    MFM(b0);
    WAIT4;
    BAR;
    LDA(1);
    MFM(b1);
  }
#undef BODY

  // epilogue: C/D col=idx, row=4g+j within each 16x16 frag (verified)
  if constexpr (SCORE) {
    short* S = (short*)Cout;
#pragma unroll
    for (int mf = 0; mf < MF; ++mf) {
#pragma unroll
      for (int j = 0; j < 4; ++j) {
        const int row = row0 + wm * (256 / WM) + mf * 16 + g * 4 + j;
        float ss = 0.f;
#pragma unroll
        for (int nf = 0; nf < 4; ++nf) {
          const float v = acc[mf][nf][j];
          ss += v * v;
          S[(size_t)row * N + col0 + wn * 64 + nf * 16 + idx] = f2bf(v);
        }
        ss += __shfl_xor(ss, 1);
        ss += __shfl_xor(ss, 2);
        ss += __shfl_xor(ss, 4);
        ss += __shfl_xor(ss, 8);
        if (idx == 0) atomicAdd(&rowss[row], ss);
      }
    }
  } else {
    float* C = (float*)Cout;
#pragma unroll
    for (int mf = 0; mf < MF; ++mf)
#pragma unroll
      for (int j = 0; j < 4; ++j) {
        const int row = row0 + wm * (256 / WM) + mf * 16 + g * 4 + j;
#pragma unroll
        for (int nf = 0; nf < 4; ++nf)
          C[(size_t)row * N + col0 + wn * 64 + nf * 16 + idx] = acc[mf][nf][j];
      }
  }
}

// ---------------- normalize + exact GELU ----------------
__global__ void norm_gelu_kernel(short* __restrict__ S,
                                 const float* __restrict__ rowss, int total8) {
  int i = blockIdx.x * blockDim.x + threadIdx.x;
  if (i >= total8) return;
  size_t base = (size_t)i * 8;
  int row = (int)(base >> 12);
  float scale = 64.0f * rsqrtf(rowss[row]);
  short8 v = *(short8*)(S + base);
  short8 o;
#pragma unroll
  for (int k = 0; k < 8; ++k) {
    float x = bf2f(v[k]) * scale;
    float gl = 0.5f * x * (1.0f + erff(x * 0.70710678118654752f));
    o[k] = f2bf(gl);
  }
  *(short8*)(S + base) = o;
}

extern "C" void kernel_launch(void* const* d_in, const int* in_sizes, int n_in,
                              void* d_out, int out_size, void* d_ws,
                              size_t ws_size, hipStream_t stream) {
  const float* X = (const float*)d_in[0];
  const float* Kp = (const float*)d_in[1];
  const float* Vp = (const float*)d_in[2];
  float* out = (float*)d_out;

  const int M = 8192, D1 = 1024, Nn = 4096, D2 = 1024;

  char* ws = (char*)d_ws;
  short* Xb = (short*)ws; ws += (size_t)M * D1 * 2;
  short* Kb = (short*)ws; ws += (size_t)Nn * D1 * 2;
  short* Vt = (short*)ws; ws += (size_t)D2 * Nn * 2;
  short* S  = (short*)ws; ws += (size_t)M * Nn * 2;
  float* rowss = (float*)ws;
  (void)ws_size;

  hipMemsetAsync(rowss, 0, M * sizeof(float), stream);
  const int n8x = M * D1 / 8, n8k = Nn * D1 / 8;
  cvt2_kernel<<<(n8x + n8k + 255) / 256, 256, 0, stream>>>(X, Kp, Xb, Kb, n8x, n8x + n8k);
  transpose_bf16_kernel<<<dim3(Nn / 64, D2 / 64), 256, 0, stream>>>(Vp, Vt, Nn, D2);

  // GEMM1: scores (bf16) + row sum-of-squares. grid = 32x16 = 512 blocks.
  gemm_hyb<4096, 1024, 256, 2, 4, true><<<512, 512, 0, stream>>>(Xb, Kb, S, rowss);
  norm_gelu_kernel<<<(M * Nn / 8 + 255) / 256, 256, 0, stream>>>(S, rowss, M * Nn / 8);
  // GEMM2: out (f32). grid = 32x8 = 256 blocks.
  gemm_hyb<1024, 4096, 128, 4, 2, false><<<256, 512, 0, stream>>>(S, Vt, out, nullptr);
}

// Round 10
// 202.864 us; speedup vs baseline: 1.6024x; 1.6024x over previous
//
#include <hip/hip_runtime.h>
#include <hip/hip_bf16.h>
#include <math.h>
#include <stdint.h>

typedef __attribute__((ext_vector_type(8))) short short8;
typedef __attribute__((ext_vector_type(4))) float f32x4;

__device__ inline short f2bf(float x) {
  union { float f; uint32_t u; } c; c.f = x;
  uint32_t r = (c.u + 0x7FFFu + ((c.u >> 16) & 1u)) >> 16;
  return (short)(uint16_t)r;
}
__device__ inline float bf2f(short s) {
  union { uint32_t u; float f; } c; c.u = ((uint32_t)(uint16_t)s) << 16;
  return c.f;
}

__device__ inline void gload16(const short* src, const char* ldsdst) {
  __builtin_amdgcn_global_load_lds(
      (const __attribute__((address_space(1))) void*)src,
      (__attribute__((address_space(3))) void*)ldsdst, 16, 0, 0);
}

// ---------------- prep: f32 -> bf16 for X and Kp in one launch ----------------
__global__ void cvt2_kernel(const float* __restrict__ X, const float* __restrict__ Kp,
                            short* __restrict__ Xb, short* __restrict__ Kb,
                            int n8x, int n8tot) {
  int i = blockIdx.x * blockDim.x + threadIdx.x;
  if (i >= n8tot) return;
  const float* src = (i < n8x) ? X + (size_t)i * 8 : Kp + (size_t)(i - n8x) * 8;
  short* dst = (i < n8x) ? Xb + (size_t)i * 8 : Kb + (size_t)(i - n8x) * 8;
  const float4* p = (const float4*)src;
  float4 a = p[0], b = p[1];
  short8 o;
  o[0] = f2bf(a.x); o[1] = f2bf(a.y); o[2] = f2bf(a.z); o[3] = f2bf(a.w);
  o[4] = f2bf(b.x); o[5] = f2bf(b.y); o[6] = f2bf(b.z); o[7] = f2bf(b.w);
  *(short8*)dst = o;
}

// ---------------- prep: V[4096,1024] f32 -> Vt[1024,4096] bf16 ----------------
__global__ void transpose_bf16_kernel(const float* __restrict__ V,
                                      short* __restrict__ Vt,
                                      int rows, int cols) {
  __shared__ float tile[64][65];
  int n0 = blockIdx.x * 64;
  int d0 = blockIdx.y * 64;
  int t = threadIdx.x;
#pragma unroll
  for (int r = 0; r < 16; ++r) {
    int idx = t + 256 * r;
    int rr = idx >> 6, cc = idx & 63;
    tile[rr][cc] = V[(size_t)(n0 + rr) * cols + d0 + cc];
  }
  __syncthreads();
#pragma unroll
  for (int r = 0; r < 16; ++r) {
    int idx = t + 256 * r;
    int dd = idx >> 6, nn = idx & 63;
    Vt[(size_t)(d0 + dd) * rows + n0 + nn] = f2bf(tile[nn][dd]);
  }
}

// ======== m97-config GEMM: C[8192,N] = A[8192,K] x B[N,K]^T ========
// 128x128 tile, BK=64, 4 waves (2x2, wave tile 64x64), 32 KiB LDS,
// {stage -> __syncthreads -> ds_read -> 32 MFMA -> __syncthreads} loop.
// __syncthreads gives full fence + vmcnt/lgkm drain semantics (race-free);
// 3 blocks/CU provide implicit cross-block pipelining (m114).
template <int N, int K, bool SCORE>
__global__ __launch_bounds__(256, 3) void gemm128(
    const short* __restrict__ A, const short* __restrict__ Bm,
    void* __restrict__ Cout, float* __restrict__ rowss) {
  constexpr int NTN = N / 128;
  constexpr int NWG = 64 * NTN;  // (8192/128) x NTN
  __shared__ char lds[32768];    // A 16K @0, B 16K @16384

  const int t = threadIdx.x, lane = t & 63;
  const int w = t >> 6, wm = w >> 1, wn = w & 1;
  const int idx = lane & 15, g = lane >> 4;

  const int bid = blockIdx.x;
  const int id2 = (bid & 7) * (NWG / 8) + (bid >> 3);  // bijective XCD swizzle
  const int row0 = (id2 / NTN) * 128, col0 = (id2 % NTN) * 128;

  // staging: thread t writes LDS byte t*16 (row t>>3, 16B-slot m=t&7) of a
  // 32-row round; content = logical k-slot m ^ (row&7)  -> source offset:
  const int sxor = ((t & 7) ^ ((t >> 3) & 7)) * 8;
  const short* gAp = A + (size_t)(row0 + (t >> 3)) * K + sxor;
  const short* gBp = Bm + (size_t)(col0 + (t >> 3)) * K + sxor;
  char* dA = (char*)lds + t * 16;
  char* dB = (char*)lds + 16384 + t * 16;

  // reads: logical slot q of row r lives at slot q ^ (r&7); r&7 == idx&7.
  // q = ks*4 + g  (ks = k-half of the 64-wide tile)
  const int s0 = (g ^ (idx & 7)) << 4;
  const int s1 = ((4 + g) ^ (idx & 7)) << 4;
  const char* rA = (char*)lds + (wm * 64 + idx) * 128;
  const char* rB = (char*)lds + 16384 + (wn * 64 + idx) * 128;

  f32x4 acc[4][4] = {};

  for (int kt = 0; kt < K; kt += 64) {
#pragma unroll
    for (int r = 0; r < 4; ++r) {
      gload16(gAp + (size_t)(r * 32) * K + kt, dA + r * 4096);
      gload16(gBp + (size_t)(r * 32) * K + kt, dB + r * 4096);
    }
    __syncthreads();  // full fence: all DMAs visible to all waves
    short8 a[4][2], b[4][2];
#pragma unroll
    for (int f = 0; f < 4; ++f) {
      a[f][0] = *(const short8*)(rA + f * 2048 + s0);
      a[f][1] = *(const short8*)(rA + f * 2048 + s1);
      b[f][0] = *(const short8*)(rB + f * 2048 + s0);
      b[f][1] = *(const short8*)(rB + f * 2048 + s1);
    }
#pragma unroll
    for (int ks = 0; ks < 2; ++ks)
#pragma unroll
      for (int f = 0; f < 4; ++f)
#pragma unroll
        for (int nf = 0; nf < 4; ++nf)
          acc[f][nf] = __builtin_amdgcn_mfma_f32_16x16x32_bf16(
              a[f][ks], b[nf][ks], acc[f][nf], 0, 0, 0);
    __syncthreads();  // all reads done before next-tile DMA overwrite
  }

  // epilogue: C/D col=idx, row=4g+j within each 16x16 frag (verified R1-R9)
  if constexpr (SCORE) {
    short* S = (short*)Cout;
#pragma unroll
    for (int mf = 0; mf < 4; ++mf) {
#pragma unroll
      for (int j = 0; j < 4; ++j) {
        const int row = row0 + wm * 64 + mf * 16 + g * 4 + j;
        float ss = 0.f;
#pragma unroll
        for (int nf = 0; nf < 4; ++nf) {
          const float v = acc[mf][nf][j];
          ss += v * v;
          S[(size_t)row * N + col0 + wn * 64 + nf * 16 + idx] = f2bf(v);
        }
        ss += __shfl_xor(ss, 1);
        ss += __shfl_xor(ss, 2);
        ss += __shfl_xor(ss, 4);
        ss += __shfl_xor(ss, 8);
        if (idx == 0) atomicAdd(&rowss[row], ss);
      }
    }
  } else {
    float* C = (float*)Cout;
#pragma unroll
    for (int mf = 0; mf < 4; ++mf)
#pragma unroll
      for (int j = 0; j < 4; ++j) {
        const int row = row0 + wm * 64 + mf * 16 + g * 4 + j;
#pragma unroll
        for (int nf = 0; nf < 4; ++nf)
          C[(size_t)row * N + col0 + wn * 64 + nf * 16 + idx] = acc[mf][nf][j];
      }
  }
}

// ---------------- normalize + exact GELU ----------------
__global__ void norm_gelu_kernel(short* __restrict__ S,
                                 const float* __restrict__ rowss, int total8) {
  int i = blockIdx.x * blockDim.x + threadIdx.x;
  if (i >= total8) return;
  size_t base = (size_t)i * 8;
  int row = (int)(base >> 12);
  float scale = 64.0f * rsqrtf(rowss[row]);
  short8 v = *(short8*)(S + base);
  short8 o;
#pragma unroll
  for (int k = 0; k < 8; ++k) {
    float x = bf2f(v[k]) * scale;
    float gl = 0.5f * x * (1.0f + erff(x * 0.70710678118654752f));
    o[k] = f2bf(gl);
  }
  *(short8*)(S + base) = o;
}

extern "C" void kernel_launch(void* const* d_in, const int* in_sizes, int n_in,
                              void* d_out, int out_size, void* d_ws,
                              size_t ws_size, hipStream_t stream) {
  const float* X = (const float*)d_in[0];
  const float* Kp = (const float*)d_in[1];
  const float* Vp = (const float*)d_in[2];
  float* out = (float*)d_out;

  const int M = 8192, D1 = 1024, Nn = 4096, D2 = 1024;

  char* ws = (char*)d_ws;
  short* Xb = (short*)ws; ws += (size_t)M * D1 * 2;
  short* Kb = (short*)ws; ws += (size_t)Nn * D1 * 2;
  short* Vt = (short*)ws; ws += (size_t)D2 * Nn * 2;
  short* S  = (short*)ws; ws += (size_t)M * Nn * 2;
  float* rowss = (float*)ws;
  (void)ws_size;

  hipMemsetAsync(rowss, 0, M * sizeof(float), stream);
  const int n8x = M * D1 / 8, n8k = Nn * D1 / 8;
  cvt2_kernel<<<(n8x + n8k + 255) / 256, 256, 0, stream>>>(X, Kp, Xb, Kb, n8x, n8x + n8k);
  transpose_bf16_kernel<<<dim3(Nn / 64, D2 / 64), 256, 0, stream>>>(Vp, Vt, Nn, D2);

  // GEMM1: scores (bf16) + row sum-of-squares. grid = 64x32 = 2048 blocks.
  gemm128<4096, 1024, true><<<2048, 256, 0, stream>>>(Xb, Kb, S, rowss);
  norm_gelu_kernel<<<(M * Nn / 8 + 255) / 256, 256, 0, stream>>>(S, rowss, M * Nn / 8);
  // GEMM2: out (f32). grid = 64x8 = 512 blocks.
  gemm128<1024, 4096, false><<<512, 256, 0, stream>>>(S, Vt, out, nullptr);
}